// Round 3
// baseline (2217.082 us; speedup 1.0000x reference)
//
#include <hip/hip_runtime.h>
#include <hip/hip_bf16.h>

#define B_   256
#define NV_  35709
#define M_   (NV_*3)      // 107127
#define NF_  70789
#define NK_  68
#define CST_ 257          // coeff row stride (elements)

typedef short bf16x8 __attribute__((ext_vector_type(8)));
typedef float f32x4  __attribute__((ext_vector_type(4)));

__device__ inline float bf2f(unsigned short u){
  union { float f; unsigned int i; } w; w.i = ((unsigned int)u) << 16; return w.f;
}
__device__ inline unsigned short f2bf(float f){
  union { float f; unsigned int i; } w; w.f = f;
  unsigned int x = w.i;
  unsigned int lsb = (x >> 16) & 1u;
  x += 0x7fffu + lsb;                 // round-to-nearest-even
  return (unsigned short)(x >> 16);
}
__device__ inline f32x4 zero4(){ f32x4 z; z.x=0.f; z.y=0.f; z.z=0.f; z.w=0.f; return z; }

// dtype-flexible input loads (flags decided on-device by k_sniff; expected: f32 floats, ints maybe i64)
__device__ inline float ldF(const void* p, size_t i, bool f32){
  return f32 ? ((const float*)p)[i] : bf2f(((const unsigned short*)p)[i]);
}
__device__ inline int ldI(const void* p, size_t i, bool i64){
  return i64 ? ((const int*)p)[2*i] : ((const int*)p)[i];   // little-endian low word
}
__device__ inline unsigned short ldBF(const void* p, size_t i, bool f32){
  if (f32) return f2bf(((const float*)p)[i]);
  return ((const unsigned short*)p)[i];
}
__device__ inline bf16x8 ldB8(const void* base, size_t off, bool f32){
  if (f32){
    const float* p = (const float*)base + off;
    bf16x8 r;
    #pragma unroll
    for (int j=0;j<8;j++) r[j] = (short)f2bf(p[j]);
    return r;
  }
  return *(const bf16x8*)((const unsigned short*)base + off);
}

// ws_small layout (floats): [0..3) mean3 | [3] f32flag | [4] i64flag
//                           [16..16+256*9) R (=Rz*Ry*Rx row-major) | [2320..2320+256*27) gT
#define WS_F32_ 3
#define WS_I64_ 4
#define WS_R_   16
#define WS_G_   2320

// ---------------- sniff: decide input dtypes on-device ----------------
__global__ void k_sniff(const unsigned int* __restrict__ mt,
                        const unsigned int* __restrict__ tri,
                        float* __restrict__ ws)
{
  int t = threadIdx.x;
  if (t < 64){
    // meantex ~ N(128,50): bf16-packed -> low halfword's high byte is 0x42/0x43 almost always;
    // fp32 -> that byte is mid-mantissa (uniform). >=16 hits of 64 => bf16.
    unsigned int w = mt[t];
    unsigned int byte = (w >> 8) & 0xFFu;
    unsigned long long m = __ballot(byte == 0x42u || byte == 0x43u);
    if (t == 0) ws[WS_F32_] = (__popcll(m) >= 16) ? 0.f : 1.f;
  } else {
    // tri in [0, 35709): int64 -> every odd 32-bit word is 0
    unsigned int w = tri[t - 64];
    unsigned long long m = __ballot(w == 0u);
    if (t == 64) ws[WS_I64_] = (__popcll(m) >= 8) ? 1.f : 0.f;
  }
}

// ---------------- K0: mean3 over meanshape + per-batch rotation & gamma ----------------
__global__ void k0_prep(const void* __restrict__ coeff,
                        const void* __restrict__ meanshape,
                        float* __restrict__ ws_small)
{
  __shared__ float r0[1024], r1[1024], r2[1024];
  const bool f32 = (ws_small[WS_F32_] != 0.f);
  int t = threadIdx.x;
  float s0=0.f, s1=0.f, s2=0.f;
  for (int v = t; v < NV_; v += 1024){
    s0 += ldF(meanshape, 3*v+0, f32);
    s1 += ldF(meanshape, 3*v+1, f32);
    s2 += ldF(meanshape, 3*v+2, f32);
  }
  r0[t]=s0; r1[t]=s1; r2[t]=s2;
  __syncthreads();
  for (int off=512; off>0; off>>=1){
    if (t < off){ r0[t]+=r0[t+off]; r1[t]+=r1[t+off]; r2[t]+=r2[t+off]; }
    __syncthreads();
  }
  if (t == 0){
    ws_small[0] = r0[0]/(float)NV_;
    ws_small[1] = r1[0]/(float)NV_;
    ws_small[2] = r2[0]/(float)NV_;
  }
  if (t < B_){
    size_t cb = (size_t)t*CST_;
    float ax = ldF(coeff, cb+224, f32), ay = ldF(coeff, cb+225, f32), az = ldF(coeff, cb+226, f32);
    float sx = __sinf(ax), cx = __cosf(ax);
    float sy = __sinf(ay), cy = __cosf(ay);
    float sz = __sinf(az), cz = __cosf(az);
    // M3 = Rz*Ry*Rx ; face_projection_row = M3 * fs_vec + trans
    float* R = ws_small + WS_R_ + t*9;
    R[0]=cz*cy;  R[1]=-sz*cx + cz*sy*sx;  R[2]= sz*sx + cz*sy*cx;
    R[3]=sz*cy;  R[4]= cz*cx + sz*sy*sx;  R[5]=-cz*sx + sz*sy*cx;
    R[6]=-sy;    R[7]= cy*sx;             R[8]= cy*cx;
    float* g = ws_small + WS_G_ + t*27;   // g[k*3+c] = gamma[a, c*9+k] (+0.8 at k=0)
    #pragma unroll
    for (int k=0;k<9;k++)
      #pragma unroll
      for (int ch=0;ch<3;ch++)
        g[k*3+ch] = ldF(coeff, cb + 227 + ch*9 + k, f32) + (k==0 ? 0.8f : 0.f);
  }
}

// ---------------- K2: MFMA GEMM -> face_shape (f32 into fp_out) and face_texture (f32 into fc_out) ----
// block tile: 64 batches (blockIdx.x of 4) x 64 rows of M (blockIdx.y of 1674)
// LDS coeff tile [64 a][264 cols]: 0..143 = id+ex coeffs, 144..159 = 0, 160..239 = tex coeffs, 240..263 = 0.
__global__ __launch_bounds__(256, 4) void k2_gemm(
    const void* __restrict__ coeff,
    const void* __restrict__ meanshape,
    const void* __restrict__ idBase,
    const void* __restrict__ exBase,
    const void* __restrict__ meantex,
    const void* __restrict__ texBase,
    const float* __restrict__ ws_small,
    float* __restrict__ fs_out,             // [B][M] f32 (fp_out region, projected later in-place)
    float* __restrict__ tex_out)            // [B][M] f32 (fc_out region, lit later in-place)
{
  __shared__ __align__(16) unsigned short sc[64*264];
  const bool f32 = (ws_small[WS_F32_] != 0.f);
  const int tid = threadIdx.x;
  const int a0 = blockIdx.x * 64;
  const int i0 = blockIdx.y * 64;
  for (int idx = tid; idx < 64*264; idx += 256){
    int row = idx / 264;
    int col = idx - row*264;
    unsigned short v = 0;
    if (col < 144)                     v = ldBF(coeff, (size_t)(a0+row)*CST_ + col, f32);
    else if (col >= 160 && col < 240)  v = ldBF(coeff, (size_t)(a0+row)*CST_ + col - 16, f32);
    sc[idx] = v;
  }
  __syncthreads();

  const int lane = tid & 63;
  const int wave = tid >> 6;
  const int quad = lane >> 4;
  const int l16  = lane & 15;
  const unsigned short* arow = &sc[(wave*16 + l16)*264];

  int irow[4];
  #pragma unroll
  for (int u=0;u<4;u++){ int i = i0 + u*16 + l16; irow[u] = (i < M_) ? i : (M_-1); }

  // ---- phase 1: face_shape, K padded to 160 ----
  f32x4 acc[4];
  #pragma unroll
  for (int u=0;u<4;u++) acc[u] = zero4();
  #pragma unroll
  for (int ks=0; ks<5; ks++){
    const int kq = ks*32 + quad*8;           // this lane's k-chunk start
    bf16x8 af = *(const bf16x8*)(arow + kq);
    #pragma unroll
    for (int u=0;u<4;u++){
      const void* bb; size_t off;
      if (kq < 80)       { bb = idBase; off = (size_t)irow[u]*80 + kq; }
      else if (kq < 144) { bb = exBase; off = (size_t)irow[u]*64 + (kq-80); }
      else               { bb = exBase; off = (size_t)irow[u]*64 + (kq-96); } // A cols 144..159 are 0
      bf16x8 bf = ldB8(bb, off, f32);
      acc[u] = __builtin_amdgcn_mfma_f32_16x16x32_bf16(af, bf, acc[u], 0, 0, 0);
    }
  }
  {
    const float m30 = ws_small[0], m31 = ws_small[1], m32 = ws_small[2];
    #pragma unroll
    for (int u=0;u<4;u++){
      int i = i0 + u*16 + l16;
      if (i < M_){
        int im3 = i % 3;
        float msv = ldF(meanshape, i, f32) - (im3==0 ? m30 : (im3==1 ? m31 : m32));
        int ab = a0 + wave*16 + quad*4;
        #pragma unroll
        for (int r=0;r<4;r++)
          fs_out[(size_t)(ab+r)*M_ + i] = acc[u][r] + msv;
      }
    }
  }

  // ---- phase 2: face_texture, K padded to 96 (LDS cols 160..255) ----
  #pragma unroll
  for (int u=0;u<4;u++) acc[u] = zero4();
  #pragma unroll
  for (int ks=0; ks<3; ks++){
    const int kq = 160 + ks*32 + quad*8;
    bf16x8 af = *(const bf16x8*)(arow + kq);
    const int kl = kq - 160;                     // 0..88
    const int koff = (kl < 80) ? kl : (kl - 16); // beyond 80: A cols are 0, in-row garbage ok
    #pragma unroll
    for (int u=0;u<4;u++){
      bf16x8 bf = ldB8(texBase, (size_t)irow[u]*80 + koff, f32);
      acc[u] = __builtin_amdgcn_mfma_f32_16x16x32_bf16(af, bf, acc[u], 0, 0, 0);
    }
  }
  {
    #pragma unroll
    for (int u=0;u<4;u++){
      int i = i0 + u*16 + l16;
      if (i < M_){
        float mtv = ldF(meantex, i, f32);
        int ab = a0 + wave*16 + quad*4;
        #pragma unroll
        for (int r=0;r<4;r++)
          tex_out[(size_t)(ab+r)*M_ + i] = acc[u][r] + mtv;
      }
    }
  }
}

// ---------------- K3: vertex normals (8 gathered faces) + SH lighting + color (in-place) -------------
__global__ __launch_bounds__(256, 4) void k3_color(
    const float* __restrict__ fs,           // [B][M] f32 (fp region, pre-projection)
    const void* __restrict__ tri,
    const void* __restrict__ point_buf,
    const float* __restrict__ ws_small,
    float* __restrict__ texcol)             // in: face_texture, out: face_color
{
  int v = blockIdx.x*256 + threadIdx.x;
  if (v >= NV_) return;
  const bool i64 = (ws_small[WS_I64_] != 0.f);
  int i0[8], i1[8], i2[8];
  unsigned valid = 0;
  #pragma unroll
  for (int k=0;k<8;k++){
    int f = ldI(point_buf, (size_t)v*8+k, i64);
    bool ok = (f < NF_);                    // f == NF_ is the appended zero-normal row
    if (ok) valid |= (1u<<k);
    size_t fb = ok ? (size_t)f*3 : 0;
    i0[k] = ldI(tri, fb+0, i64)*3; i1[k] = ldI(tri, fb+1, i64)*3; i2[k] = ldI(tri, fb+2, i64)*3;
  }
  const float PI   = 3.14159265358979323846f;
  const float a1c1 = (2.f*PI/sqrtf(3.f)) * (sqrtf(3.f)/sqrtf(4.f*PI));
  const float a2c2 = (2.f*PI/sqrtf(8.f)) * (3.f*sqrtf(5.f)/sqrtf(12.f*PI));
  const float y0c  = PI * (1.f/sqrtf(4.f*PI));
  const float d0   = 0.5f/sqrtf(3.f);

  const int aBeg = blockIdx.y * 8;
  for (int t=0; t<8; t++){
    const int a = aBeg + t;
    const float* fsa = fs + (size_t)a*M_;
    float nx=0.f, ny=0.f, nz=0.f;
    #pragma unroll
    for (int k=0;k<8;k++){
      if (!(valid & (1u<<k))) continue;
      float ax=fsa[i0[k]+0], ay=fsa[i0[k]+1], az=fsa[i0[k]+2];
      float bx=fsa[i1[k]+0], by=fsa[i1[k]+1], bz=fsa[i1[k]+2];
      float cx=fsa[i2[k]+0], cy=fsa[i2[k]+1], cz=fsa[i2[k]+2];
      float e1x=ax-bx, e1y=ay-by, e1z=az-bz;
      float e2x=bx-cx, e2y=by-cy, e2z=bz-cz;
      nx += e1y*e2z - e1z*e2y;
      ny += e1z*e2x - e1x*e2z;
      nz += e1x*e2y - e1y*e2x;
    }
    float inv = rsqrtf(nx*nx + ny*ny + nz*nz);
    nx*=inv; ny*=inv; nz*=inv;
    float Y1 = -a1c1*ny, Y2 = a1c1*nz, Y3 = -a1c1*nx;
    float Y4 =  a2c2*nx*ny, Y5 = -a2c2*ny*nz, Y6 = a2c2*d0*(3.f*nz*nz - 1.f);
    float Y7 = -a2c2*nx*nz, Y8 = a2c2*0.5f*(nx*nx - ny*ny);
    const float* g = ws_small + WS_G_ + a*27;
    size_t base = (size_t)a*M_ + (size_t)v*3;
    #pragma unroll
    for (int c=0;c<3;c++){
      float L = y0c*g[c]   + Y1*g[3+c]  + Y2*g[6+c]  + Y3*g[9+c]  + Y4*g[12+c]
              + Y5*g[15+c] + Y6*g[18+c] + Y7*g[21+c] + Y8*g[24+c];
      float tx  = texcol[base+c];
      float col = tx * L * (1.f/255.f);
      col = fminf(fmaxf(col, 0.f), 1.f);
      texcol[base+c] = col;
    }
  }
}

// ---------------- K4: rigid projection (in-place per element) ----------------
__global__ __launch_bounds__(256, 4) void k4_proj(
    const void* __restrict__ coeff,
    const float* __restrict__ ws_small,
    float* __restrict__ fp)                 // in: face_shape f32, out: projection f32
{
  int v = blockIdx.x*256 + threadIdx.x;
  if (v >= NV_) return;
  const bool f32 = (ws_small[WS_F32_] != 0.f);
  int a = blockIdx.y;
  const float* R = ws_small + WS_R_ + a*9;
  size_t cb = (size_t)a*CST_;
  float t0 = ldF(coeff, cb+254, f32);
  float t1 = ldF(coeff, cb+255, f32);
  float t2 = ldF(coeff, cb+256, f32);
  size_t base = (size_t)a*M_ + (size_t)v*3;
  float f0 = fp[base+0], f1 = fp[base+1], f2v = fp[base+2];
  float p0 = R[0]*f0 + R[1]*f1 + R[2]*f2v + t0;
  float p1 = R[3]*f0 + R[4]*f1 + R[5]*f2v + t1;
  float p2 = R[6]*f0 + R[7]*f1 + R[8]*f2v + t2;
  fp[base+0] = p0;
  fp[base+1] = p1;
  fp[base+2] = p2;
}

// ---------------- K5: landmark gather ----------------
__global__ void k5_lm(const float* __restrict__ fp,
                      const void* __restrict__ keypoints,
                      const float* __restrict__ ws_small,
                      float* __restrict__ lm)
{
  int e = blockIdx.x*256 + threadIdx.x;          // over B*NK*3
  if (e >= B_*NK_*3) return;
  const bool i64 = (ws_small[WS_I64_] != 0.f);
  int c = e % 3;
  int rest = e / 3;
  int k = rest % NK_;
  int a = rest / NK_;
  lm[e] = fp[(size_t)a*M_ + (size_t)ldI(keypoints, k, i64)*3 + c];
}

// ---------------- K6: tri -> f32 ----------------
__global__ void k6_tri(const void* __restrict__ tri,
                       const float* __restrict__ ws_small,
                       float* __restrict__ out)
{
  int e = blockIdx.x*256 + threadIdx.x;
  if (e >= NF_*3) return;
  const bool i64 = (ws_small[WS_I64_] != 0.f);
  out[e] = (float)ldI(tri, e, i64);
}

extern "C" void kernel_launch(void* const* d_in, const int* in_sizes, int n_in,
                              void* d_out, int out_size, void* d_ws, size_t ws_size,
                              hipStream_t stream)
{
  const void* coeff     = d_in[0];
  const void* meanshape = d_in[1];
  const void* idBase    = d_in[2];
  const void* exBase    = d_in[3];
  const void* meantex   = d_in[4];
  const void* texBase   = d_in[5];
  const void* tri       = d_in[6];
  const void* point_buf = d_in[7];
  const void* keypoints = d_in[8];

  float* out    = (float*)d_out;
  float* fp_out = out;                               // B*M
  float* fc_out = out + (size_t)B_*M_;               // B*M
  float* lm_out = fc_out + (size_t)B_*M_;            // B*NK*3
  float* tri_out= lm_out + (size_t)B_*NK_*3;         // NF*3

  float* ws_small = (float*)d_ws;

  k_sniff<<<1, 128, 0, stream>>>((const unsigned int*)meantex, (const unsigned int*)tri, ws_small);
  k0_prep<<<1, 1024, 0, stream>>>(coeff, meanshape, ws_small);

  dim3 g2(B_/64, (M_ + 63)/64);     // (4, 1674): x = a-tile (fast) -> L2 reuse of base rows
  dim3 g3((NV_ + 255)/256, B_/8);   // (140, 32)
  dim3 g4((NV_ + 255)/256, B_);     // (140, 256)

  k2_gemm<<<g2, 256, 0, stream>>>(coeff, meanshape, idBase, exBase, meantex, texBase,
                                  ws_small, fp_out, fc_out);
  k3_color<<<g3, 256, 0, stream>>>(fp_out, tri, point_buf, ws_small, fc_out);
  k4_proj<<<g4, 256, 0, stream>>>(coeff, ws_small, fp_out);
  k5_lm<<<(B_*NK_*3 + 255)/256, 256, 0, stream>>>(fp_out, keypoints, ws_small, lm_out);
  k6_tri<<<(NF_*3 + 255)/256, 256, 0, stream>>>(tri, ws_small, tri_out);
}

// Round 4
// 1060.213 us; speedup vs baseline: 2.0912x; 2.0912x over previous
//
#include <hip/hip_runtime.h>
#include <hip/hip_bf16.h>

#define B_   256
#define NV_  35709
#define M_   (NV_*3)      // 107127
#define NF_  70789
#define NK_  68
#define CST_ 257          // coeff row stride (elements)

typedef short bf16x8 __attribute__((ext_vector_type(8)));
typedef float f32x4  __attribute__((ext_vector_type(4)));

__device__ inline float bf2f(unsigned short u){
  union { float f; unsigned int i; } w; w.i = ((unsigned int)u) << 16; return w.f;
}
__device__ inline unsigned short f2bf(float f){
  union { float f; unsigned int i; } w; w.f = f;
  unsigned int x = w.i;
  unsigned int lsb = (x >> 16) & 1u;
  x += 0x7fffu + lsb;                 // round-to-nearest-even
  return (unsigned short)(x >> 16);
}
__device__ inline f32x4 zero4(){ f32x4 z; z.x=0.f; z.y=0.f; z.z=0.f; z.w=0.f; return z; }

// dtype-flexible input loads (flags decided on-device by k_sniff)
__device__ inline float ldF(const void* p, size_t i, bool f32){
  return f32 ? ((const float*)p)[i] : bf2f(((const unsigned short*)p)[i]);
}
__device__ inline int ldI(const void* p, size_t i, bool i64){
  return i64 ? ((const int*)p)[2*i] : ((const int*)p)[i];   // little-endian low word
}
__device__ inline unsigned short ldBF(const void* p, size_t i, bool f32){
  if (f32) return f2bf(((const float*)p)[i]);
  return ((const unsigned short*)p)[i];
}
__device__ inline bf16x8 ldB8(const void* base, size_t off, bool f32){
  if (f32){
    const float* p = (const float*)base + off;
    bf16x8 r;
    #pragma unroll
    for (int j=0;j<8;j++) r[j] = (short)f2bf(p[j]);
    return r;
  }
  return *(const bf16x8*)((const unsigned short*)base + off);
}

// ws_small layout (floats): [0..3) mean3 | [3] f32flag | [4] i64flag
//                           [16..16+256*9) R (=Rz*Ry*Rx row-major) | [2320..2320+256*27) gT
#define WS_F32_ 3
#define WS_I64_ 4
#define WS_R_   16
#define WS_G_   2320

// ---------------- sniff: decide input dtypes on-device ----------------
__global__ void k_sniff(const unsigned int* __restrict__ mt,
                        const unsigned int* __restrict__ tri,
                        float* __restrict__ ws)
{
  int t = threadIdx.x;
  if (t < 64){
    unsigned int w = mt[t];
    unsigned int byte = (w >> 8) & 0xFFu;
    unsigned long long m = __ballot(byte == 0x42u || byte == 0x43u);
    if (t == 0) ws[WS_F32_] = (__popcll(m) >= 16) ? 0.f : 1.f;
  } else {
    unsigned int w = tri[t - 64];
    unsigned long long m = __ballot(w == 0u);
    if (t == 64) ws[WS_I64_] = (__popcll(m) >= 8) ? 1.f : 0.f;
  }
}

// ---------------- K0: mean3 over meanshape + per-batch rotation & gamma ----------------
__global__ void k0_prep(const void* __restrict__ coeff,
                        const void* __restrict__ meanshape,
                        float* __restrict__ ws_small)
{
  __shared__ float r0[1024], r1[1024], r2[1024];
  const bool f32 = (ws_small[WS_F32_] != 0.f);
  int t = threadIdx.x;
  float s0=0.f, s1=0.f, s2=0.f;
  for (int v = t; v < NV_; v += 1024){
    s0 += ldF(meanshape, 3*v+0, f32);
    s1 += ldF(meanshape, 3*v+1, f32);
    s2 += ldF(meanshape, 3*v+2, f32);
  }
  r0[t]=s0; r1[t]=s1; r2[t]=s2;
  __syncthreads();
  for (int off=512; off>0; off>>=1){
    if (t < off){ r0[t]+=r0[t+off]; r1[t]+=r1[t+off]; r2[t]+=r2[t+off]; }
    __syncthreads();
  }
  if (t == 0){
    ws_small[0] = r0[0]/(float)NV_;
    ws_small[1] = r1[0]/(float)NV_;
    ws_small[2] = r2[0]/(float)NV_;
  }
  if (t < B_){
    size_t cb = (size_t)t*CST_;
    float ax = ldF(coeff, cb+224, f32), ay = ldF(coeff, cb+225, f32), az = ldF(coeff, cb+226, f32);
    float sx = __sinf(ax), cx = __cosf(ax);
    float sy = __sinf(ay), cy = __cosf(ay);
    float sz = __sinf(az), cz = __cosf(az);
    float* R = ws_small + WS_R_ + t*9;
    R[0]=cz*cy;  R[1]=-sz*cx + cz*sy*sx;  R[2]= sz*sx + cz*sy*cx;
    R[3]=sz*cy;  R[4]= cz*cx + sz*sy*sx;  R[5]=-cz*sx + sz*sy*cx;
    R[6]=-sy;    R[7]= cy*sx;             R[8]= cy*cx;
    float* g = ws_small + WS_G_ + t*27;
    #pragma unroll
    for (int k=0;k<9;k++)
      #pragma unroll
      for (int ch=0;ch<3;ch++)
        g[k*3+ch] = ldF(coeff, cb + 227 + ch*9 + k, f32) + (k==0 ? 0.8f : 0.f);
  }
}

// =====================================================================================
// NEW PATH: [element][batch]-major bf16 intermediates in ws
// =====================================================================================

// ---- K2T: MFMA GEMM, A = base rows (m=i), B = coeff (n=a). Output [i][a]-major bf16. ----
__global__ __launch_bounds__(256, 4) void k2t_gemm(
    const void* __restrict__ coeff,
    const void* __restrict__ meanshape,
    const void* __restrict__ idBase,
    const void* __restrict__ exBase,
    const void* __restrict__ meantex,
    const void* __restrict__ texBase,
    const float* __restrict__ ws_small,
    unsigned short* __restrict__ fs_t,      // [M][B] bf16
    unsigned short* __restrict__ tex_t)     // [M][B] bf16
{
  __shared__ __align__(16) unsigned short sc[64*264];
  const bool f32 = (ws_small[WS_F32_] != 0.f);
  const int tid = threadIdx.x;
  const int a0 = blockIdx.x * 64;
  const int i0 = blockIdx.y * 64;
  for (int idx = tid; idx < 64*264; idx += 256){
    int row = idx / 264;
    int col = idx - row*264;
    unsigned short v = 0;
    if (col < 144)                     v = ldBF(coeff, (size_t)(a0+row)*CST_ + col, f32);
    else if (col >= 160 && col < 240)  v = ldBF(coeff, (size_t)(a0+row)*CST_ + col - 16, f32);
    sc[idx] = v;
  }
  __syncthreads();

  const int lane = tid & 63;
  const int wave = tid >> 6;
  const int quad = lane >> 4;
  const int l16  = lane & 15;
  const int ib   = i0 + wave*16;                 // wave's 16-row i-tile
  int irow = ib + l16; if (irow >= M_) irow = M_-1;

  // ---- phase 1: face_shape, K padded to 160 ----
  f32x4 acc[4];
  #pragma unroll
  for (int u=0;u<4;u++) acc[u] = zero4();
  #pragma unroll
  for (int ks=0; ks<5; ks++){
    const int kq = ks*32 + quad*8;
    const void* bb; size_t off;
    if (kq < 80)       { bb = idBase; off = (size_t)irow*80 + kq; }
    else if (kq < 144) { bb = exBase; off = (size_t)irow*64 + (kq-80); }
    else               { bb = exBase; off = (size_t)irow*64 + (kq-96); } // A cols 144..159 zero via coeff pad
    bf16x8 af = ldB8(bb, off, f32);
    #pragma unroll
    for (int u=0;u<4;u++){
      bf16x8 bf = *(const bf16x8*)(sc + (u*16+l16)*264 + kq);
      acc[u] = __builtin_amdgcn_mfma_f32_16x16x32_bf16(af, bf, acc[u], 0, 0, 0);
    }
  }
  {
    const float m30 = ws_small[0], m31 = ws_small[1], m32 = ws_small[2];
    #pragma unroll
    for (int r=0;r<4;r++){
      int i = ib + quad*4 + r;
      if (i < M_){
        int im3 = i % 3;
        float msv = ldF(meanshape, i, f32) - (im3==0 ? m30 : (im3==1 ? m31 : m32));
        #pragma unroll
        for (int u=0;u<4;u++)
          fs_t[(size_t)i*B_ + a0 + u*16 + l16] = f2bf(acc[u][r] + msv);
      }
    }
  }

  // ---- phase 2: face_texture, K padded to 96 ----
  #pragma unroll
  for (int u=0;u<4;u++) acc[u] = zero4();
  #pragma unroll
  for (int ks=0; ks<3; ks++){
    const int kq = 160 + ks*32 + quad*8;
    const int kl = kq - 160;
    const int koff = (kl < 80) ? kl : (kl - 16);
    bf16x8 af = ldB8(texBase, (size_t)irow*80 + koff, f32);
    #pragma unroll
    for (int u=0;u<4;u++){
      bf16x8 bf = *(const bf16x8*)(sc + (u*16+l16)*264 + kq);
      acc[u] = __builtin_amdgcn_mfma_f32_16x16x32_bf16(af, bf, acc[u], 0, 0, 0);
    }
  }
  {
    #pragma unroll
    for (int r=0;r<4;r++){
      int i = ib + quad*4 + r;
      if (i < M_){
        float mtv = ldF(meantex, i, f32);
        #pragma unroll
        for (int u=0;u<4;u++)
          tex_t[(size_t)i*B_ + a0 + u*16 + l16] = f2bf(acc[u][r] + mtv);
      }
    }
  }
}

// ---- K3A: per-face normals, thread = batch, fully coalesced gathers ----
#define FCH_ 16
__global__ __launch_bounds__(256) void k3a_fn(
    const unsigned short* __restrict__ fs_t,
    const void* __restrict__ tri,
    const float* __restrict__ ws_small,
    unsigned short* __restrict__ fn_t)      // [NF*3][B] bf16
{
  const bool i64 = (ws_small[WS_I64_] != 0.f);
  const int a = threadIdx.x;
  const int f0 = blockIdx.x * FCH_;
  for (int ff=0; ff<FCH_; ff++){
    int f = f0 + ff;
    if (f >= NF_) return;
    int v0 = ldI(tri, (size_t)f*3+0, i64);
    int v1 = ldI(tri, (size_t)f*3+1, i64);
    int v2 = ldI(tri, (size_t)f*3+2, i64);
    const unsigned short* p0 = fs_t + (size_t)v0*3*B_ + a;
    const unsigned short* p1 = fs_t + (size_t)v1*3*B_ + a;
    const unsigned short* p2 = fs_t + (size_t)v2*3*B_ + a;
    float ax=bf2f(p0[0]), ay=bf2f(p0[B_]), az=bf2f(p0[2*B_]);
    float bx=bf2f(p1[0]), by=bf2f(p1[B_]), bz=bf2f(p1[2*B_]);
    float cx=bf2f(p2[0]), cy=bf2f(p2[B_]), cz=bf2f(p2[2*B_]);
    float e1x=ax-bx, e1y=ay-by, e1z=az-bz;
    float e2x=bx-cx, e2y=by-cy, e2z=bz-cz;
    size_t ob = (size_t)f*3*B_ + a;
    fn_t[ob]       = f2bf(e1y*e2z - e1z*e2y);
    fn_t[ob+B_]    = f2bf(e1z*e2x - e1x*e2z);
    fn_t[ob+2*B_]  = f2bf(e1x*e2y - e1y*e2x);
  }
}

// ---- K3B: v_norm sum + SH lighting + color, thread = batch, LDS transpose to [a][i] ----
#define VCH_ 16
__global__ __launch_bounds__(256) void k3b_color(
    const unsigned short* __restrict__ fn_t,
    const unsigned short* __restrict__ tex_t,
    const void* __restrict__ point_buf,
    const float* __restrict__ ws_small,
    float* __restrict__ fc)                 // [B][M] f32 output
{
  __shared__ float gl[B_*27];
  __shared__ float tile[48*257];
  const int tid = threadIdx.x;
  const int a = tid;
  for (int e = tid; e < B_*27; e += 256) gl[e] = ws_small[WS_G_ + e];
  __syncthreads();
  const bool i64 = (ws_small[WS_I64_] != 0.f);

  const float PI   = 3.14159265358979323846f;
  const float a1c1 = (2.f*PI/sqrtf(3.f)) * (sqrtf(3.f)/sqrtf(4.f*PI));
  const float a2c2 = (2.f*PI/sqrtf(8.f)) * (3.f*sqrtf(5.f)/sqrtf(12.f*PI));
  const float y0c  = PI * (1.f/sqrtf(4.f*PI));
  const float d0   = 0.5f/sqrtf(3.f);

  const int v0 = blockIdx.x * VCH_;
  for (int vv=0; vv<VCH_; vv++){
    int v = v0 + vv;
    if (v >= NV_) break;
    float nx=0.f, ny=0.f, nz=0.f;
    #pragma unroll
    for (int k=0;k<8;k++){
      int f = ldI(point_buf, (size_t)v*8+k, i64);
      if (f < NF_){
        size_t rb = (size_t)f*3*B_ + a;
        nx += bf2f(fn_t[rb]);
        ny += bf2f(fn_t[rb+B_]);
        nz += bf2f(fn_t[rb+2*B_]);
      }
    }
    float inv = rsqrtf(nx*nx + ny*ny + nz*nz);
    nx*=inv; ny*=inv; nz*=inv;
    float Y1 = -a1c1*ny, Y2 = a1c1*nz, Y3 = -a1c1*nx;
    float Y4 =  a2c2*nx*ny, Y5 = -a2c2*ny*nz, Y6 = a2c2*d0*(3.f*nz*nz - 1.f);
    float Y7 = -a2c2*nx*nz, Y8 = a2c2*0.5f*(nx*nx - ny*ny);
    const float* g = gl + a*27;
    size_t tb = (size_t)v*3*B_ + a;
    #pragma unroll
    for (int c=0;c<3;c++){
      float L = y0c*g[c]   + Y1*g[3+c]  + Y2*g[6+c]  + Y3*g[9+c]  + Y4*g[12+c]
              + Y5*g[15+c] + Y6*g[18+c] + Y7*g[21+c] + Y8*g[24+c];
      float tx = bf2f(tex_t[tb + (size_t)c*B_]);
      float col = tx * L * (1.f/255.f);
      col = fminf(fmaxf(col, 0.f), 1.f);
      tile[(vv*3+c)*257 + a] = col;
    }
  }
  __syncthreads();
  const int base_i = v0*3;
  int lim = M_ - base_i; if (lim > 48) lim = 48;
  for (int t=0; t<48; t++){
    int idx = t*256 + tid;
    int aa = idx / 48;
    int ii = idx - aa*48;
    if (ii < lim)
      fc[(size_t)aa*M_ + base_i + ii] = tile[ii*257 + aa];
  }
}

// ---- K4T: rigid projection with LDS transpose [i][a] -> [a][i] ----
__global__ __launch_bounds__(256) void k4t_proj(
    const unsigned short* __restrict__ fs_t,
    const void* __restrict__ coeff,
    const float* __restrict__ ws_small,
    float* __restrict__ fp)                 // [B][M] f32 output
{
  __shared__ float tile[48*257];
  const int tid = threadIdx.x;
  const int base_i = blockIdx.x * 48;
  const bool f32 = (ws_small[WS_F32_] != 0.f);
  for (int t=0; t<48; t++){
    int i = base_i + t;
    float v = (i < M_) ? bf2f(fs_t[(size_t)i*B_ + tid]) : 0.f;
    tile[t*257 + tid] = v;
  }
  __syncthreads();
  int lim = M_ - base_i; if (lim > 48) lim = 48;
  for (int t=0; t<48; t++){
    int idx = t*256 + tid;
    int aa = idx / 48;
    int ii = idx - aa*48;
    if (ii < lim){
      int vv = ii / 3;
      int c  = ii - vv*3;
      float f0 = tile[(vv*3+0)*257 + aa];
      float f1 = tile[(vv*3+1)*257 + aa];
      float f2v= tile[(vv*3+2)*257 + aa];
      const float* R = ws_small + WS_R_ + aa*9 + c*3;
      float tc = ldF(coeff, (size_t)aa*CST_ + 254 + c, f32);
      fp[(size_t)aa*M_ + base_i + ii] = R[0]*f0 + R[1]*f1 + R[2]*f2v + tc;
    }
  }
}

// =====================================================================================
// OLD PATH (R3, passing) — fallback when ws is too small
// =====================================================================================
__global__ __launch_bounds__(256, 4) void k2_gemm(
    const void* __restrict__ coeff, const void* __restrict__ meanshape,
    const void* __restrict__ idBase, const void* __restrict__ exBase,
    const void* __restrict__ meantex, const void* __restrict__ texBase,
    const float* __restrict__ ws_small,
    float* __restrict__ fs_out, float* __restrict__ tex_out)
{
  __shared__ __align__(16) unsigned short sc[64*264];
  const bool f32 = (ws_small[WS_F32_] != 0.f);
  const int tid = threadIdx.x;
  const int a0 = blockIdx.x * 64;
  const int i0 = blockIdx.y * 64;
  for (int idx = tid; idx < 64*264; idx += 256){
    int row = idx / 264;
    int col = idx - row*264;
    unsigned short v = 0;
    if (col < 144)                     v = ldBF(coeff, (size_t)(a0+row)*CST_ + col, f32);
    else if (col >= 160 && col < 240)  v = ldBF(coeff, (size_t)(a0+row)*CST_ + col - 16, f32);
    sc[idx] = v;
  }
  __syncthreads();
  const int lane = tid & 63;
  const int wave = tid >> 6;
  const int quad = lane >> 4;
  const int l16  = lane & 15;
  const unsigned short* arow = &sc[(wave*16 + l16)*264];
  int irow[4];
  #pragma unroll
  for (int u=0;u<4;u++){ int i = i0 + u*16 + l16; irow[u] = (i < M_) ? i : (M_-1); }
  f32x4 acc[4];
  #pragma unroll
  for (int u=0;u<4;u++) acc[u] = zero4();
  #pragma unroll
  for (int ks=0; ks<5; ks++){
    const int kq = ks*32 + quad*8;
    bf16x8 af = *(const bf16x8*)(arow + kq);
    #pragma unroll
    for (int u=0;u<4;u++){
      const void* bb; size_t off;
      if (kq < 80)       { bb = idBase; off = (size_t)irow[u]*80 + kq; }
      else if (kq < 144) { bb = exBase; off = (size_t)irow[u]*64 + (kq-80); }
      else               { bb = exBase; off = (size_t)irow[u]*64 + (kq-96); }
      bf16x8 bf = ldB8(bb, off, f32);
      acc[u] = __builtin_amdgcn_mfma_f32_16x16x32_bf16(af, bf, acc[u], 0, 0, 0);
    }
  }
  {
    const float m30 = ws_small[0], m31 = ws_small[1], m32 = ws_small[2];
    #pragma unroll
    for (int u=0;u<4;u++){
      int i = i0 + u*16 + l16;
      if (i < M_){
        int im3 = i % 3;
        float msv = ldF(meanshape, i, f32) - (im3==0 ? m30 : (im3==1 ? m31 : m32));
        int ab = a0 + wave*16 + quad*4;
        #pragma unroll
        for (int r=0;r<4;r++)
          fs_out[(size_t)(ab+r)*M_ + i] = acc[u][r] + msv;
      }
    }
  }
  #pragma unroll
  for (int u=0;u<4;u++) acc[u] = zero4();
  #pragma unroll
  for (int ks=0; ks<3; ks++){
    const int kq = 160 + ks*32 + quad*8;
    bf16x8 af = *(const bf16x8*)(arow + kq);
    const int kl = kq - 160;
    const int koff = (kl < 80) ? kl : (kl - 16);
    #pragma unroll
    for (int u=0;u<4;u++){
      bf16x8 bf = ldB8(texBase, (size_t)irow[u]*80 + koff, f32);
      acc[u] = __builtin_amdgcn_mfma_f32_16x16x32_bf16(af, bf, acc[u], 0, 0, 0);
    }
  }
  {
    #pragma unroll
    for (int u=0;u<4;u++){
      int i = i0 + u*16 + l16;
      if (i < M_){
        float mtv = ldF(meantex, i, f32);
        int ab = a0 + wave*16 + quad*4;
        #pragma unroll
        for (int r=0;r<4;r++)
          tex_out[(size_t)(ab+r)*M_ + i] = acc[u][r] + mtv;
      }
    }
  }
}

__global__ __launch_bounds__(256, 4) void k3_color(
    const float* __restrict__ fs, const void* __restrict__ tri,
    const void* __restrict__ point_buf, const float* __restrict__ ws_small,
    float* __restrict__ texcol)
{
  int v = blockIdx.x*256 + threadIdx.x;
  if (v >= NV_) return;
  const bool i64 = (ws_small[WS_I64_] != 0.f);
  int i0[8], i1[8], i2[8];
  unsigned valid = 0;
  #pragma unroll
  for (int k=0;k<8;k++){
    int f = ldI(point_buf, (size_t)v*8+k, i64);
    bool ok = (f < NF_);
    if (ok) valid |= (1u<<k);
    size_t fb = ok ? (size_t)f*3 : 0;
    i0[k] = ldI(tri, fb+0, i64)*3; i1[k] = ldI(tri, fb+1, i64)*3; i2[k] = ldI(tri, fb+2, i64)*3;
  }
  const float PI   = 3.14159265358979323846f;
  const float a1c1 = (2.f*PI/sqrtf(3.f)) * (sqrtf(3.f)/sqrtf(4.f*PI));
  const float a2c2 = (2.f*PI/sqrtf(8.f)) * (3.f*sqrtf(5.f)/sqrtf(12.f*PI));
  const float y0c  = PI * (1.f/sqrtf(4.f*PI));
  const float d0   = 0.5f/sqrtf(3.f);
  const int aBeg = blockIdx.y * 8;
  for (int t=0; t<8; t++){
    const int a = aBeg + t;
    const float* fsa = fs + (size_t)a*M_;
    float nx=0.f, ny=0.f, nz=0.f;
    #pragma unroll
    for (int k=0;k<8;k++){
      if (!(valid & (1u<<k))) continue;
      float ax=fsa[i0[k]+0], ay=fsa[i0[k]+1], az=fsa[i0[k]+2];
      float bx=fsa[i1[k]+0], by=fsa[i1[k]+1], bz=fsa[i1[k]+2];
      float cx=fsa[i2[k]+0], cy=fsa[i2[k]+1], cz=fsa[i2[k]+2];
      float e1x=ax-bx, e1y=ay-by, e1z=az-bz;
      float e2x=bx-cx, e2y=by-cy, e2z=bz-cz;
      nx += e1y*e2z - e1z*e2y;
      ny += e1z*e2x - e1x*e2z;
      nz += e1x*e2y - e1y*e2x;
    }
    float inv = rsqrtf(nx*nx + ny*ny + nz*nz);
    nx*=inv; ny*=inv; nz*=inv;
    float Y1 = -a1c1*ny, Y2 = a1c1*nz, Y3 = -a1c1*nx;
    float Y4 =  a2c2*nx*ny, Y5 = -a2c2*ny*nz, Y6 = a2c2*d0*(3.f*nz*nz - 1.f);
    float Y7 = -a2c2*nx*nz, Y8 = a2c2*0.5f*(nx*nx - ny*ny);
    const float* g = ws_small + WS_G_ + a*27;
    size_t base = (size_t)a*M_ + (size_t)v*3;
    #pragma unroll
    for (int c=0;c<3;c++){
      float L = y0c*g[c]   + Y1*g[3+c]  + Y2*g[6+c]  + Y3*g[9+c]  + Y4*g[12+c]
              + Y5*g[15+c] + Y6*g[18+c] + Y7*g[21+c] + Y8*g[24+c];
      float tx  = texcol[base+c];
      float col = tx * L * (1.f/255.f);
      col = fminf(fmaxf(col, 0.f), 1.f);
      texcol[base+c] = col;
    }
  }
}

__global__ __launch_bounds__(256, 4) void k4_proj(
    const void* __restrict__ coeff, const float* __restrict__ ws_small,
    float* __restrict__ fp)
{
  int v = blockIdx.x*256 + threadIdx.x;
  if (v >= NV_) return;
  const bool f32 = (ws_small[WS_F32_] != 0.f);
  int a = blockIdx.y;
  const float* R = ws_small + WS_R_ + a*9;
  size_t cb = (size_t)a*CST_;
  float t0 = ldF(coeff, cb+254, f32);
  float t1 = ldF(coeff, cb+255, f32);
  float t2 = ldF(coeff, cb+256, f32);
  size_t base = (size_t)a*M_ + (size_t)v*3;
  float f0 = fp[base+0], f1 = fp[base+1], f2v = fp[base+2];
  fp[base+0] = R[0]*f0 + R[1]*f1 + R[2]*f2v + t0;
  fp[base+1] = R[3]*f0 + R[4]*f1 + R[5]*f2v + t1;
  fp[base+2] = R[6]*f0 + R[7]*f1 + R[8]*f2v + t2;
}

// ---------------- K5: landmark gather ----------------
__global__ void k5_lm(const float* __restrict__ fp,
                      const void* __restrict__ keypoints,
                      const float* __restrict__ ws_small,
                      float* __restrict__ lm)
{
  int e = blockIdx.x*256 + threadIdx.x;
  if (e >= B_*NK_*3) return;
  const bool i64 = (ws_small[WS_I64_] != 0.f);
  int c = e % 3;
  int rest = e / 3;
  int k = rest % NK_;
  int a = rest / NK_;
  lm[e] = fp[(size_t)a*M_ + (size_t)ldI(keypoints, k, i64)*3 + c];
}

// ---------------- K6: tri -> f32 ----------------
__global__ void k6_tri(const void* __restrict__ tri,
                       const float* __restrict__ ws_small,
                       float* __restrict__ out)
{
  int e = blockIdx.x*256 + threadIdx.x;
  if (e >= NF_*3) return;
  const bool i64 = (ws_small[WS_I64_] != 0.f);
  out[e] = (float)ldI(tri, e, i64);
}

extern "C" void kernel_launch(void* const* d_in, const int* in_sizes, int n_in,
                              void* d_out, int out_size, void* d_ws, size_t ws_size,
                              hipStream_t stream)
{
  const void* coeff     = d_in[0];
  const void* meanshape = d_in[1];
  const void* idBase    = d_in[2];
  const void* exBase    = d_in[3];
  const void* meantex   = d_in[4];
  const void* texBase   = d_in[5];
  const void* tri       = d_in[6];
  const void* point_buf = d_in[7];
  const void* keypoints = d_in[8];

  float* out    = (float*)d_out;
  float* fp_out = out;                               // B*M
  float* fc_out = out + (size_t)B_*M_;               // B*M
  float* lm_out = fc_out + (size_t)B_*M_;            // B*NK*3
  float* tri_out= lm_out + (size_t)B_*NK_*3;         // NF*3

  float* ws_small = (float*)d_ws;

  const size_t MB2 = (size_t)M_*B_*2;                // bf16 [M][B]
  const size_t FN2 = (size_t)NF_*3*B_*2;             // bf16 [NF*3][B]
  const size_t need = 65536 + 2*MB2 + FN2;           // ~208.4 MiB

  k_sniff<<<1, 128, 0, stream>>>((const unsigned int*)meantex, (const unsigned int*)tri, ws_small);
  k0_prep<<<1, 1024, 0, stream>>>(coeff, meanshape, ws_small);

  if (ws_size >= need){
    unsigned short* fs_t  = (unsigned short*)((char*)d_ws + 65536);
    unsigned short* tex_t = fs_t  + (size_t)M_*B_;
    unsigned short* fn_t  = tex_t + (size_t)M_*B_;

    dim3 g2(B_/64, (M_ + 63)/64);                  // (4, 1674)
    k2t_gemm<<<g2, 256, 0, stream>>>(coeff, meanshape, idBase, exBase, meantex, texBase,
                                     ws_small, fs_t, tex_t);
    k3a_fn<<<(NF_ + FCH_-1)/FCH_, 256, 0, stream>>>(fs_t, tri, ws_small, fn_t);
    k4t_proj<<<(M_ + 47)/48, 256, 0, stream>>>(fs_t, coeff, ws_small, fp_out);
    k3b_color<<<(NV_ + VCH_-1)/VCH_, 256, 0, stream>>>(fn_t, tex_t, point_buf, ws_small, fc_out);
  } else {
    dim3 g2(B_/64, (M_ + 63)/64);
    dim3 g3((NV_ + 255)/256, B_/8);
    dim3 g4((NV_ + 255)/256, B_);
    k2_gemm<<<g2, 256, 0, stream>>>(coeff, meanshape, idBase, exBase, meantex, texBase,
                                    ws_small, fp_out, fc_out);
    k3_color<<<g3, 256, 0, stream>>>(fp_out, tri, point_buf, ws_small, fc_out);
    k4_proj<<<g4, 256, 0, stream>>>(coeff, ws_small, fp_out);
  }
  k5_lm<<<(B_*NK_*3 + 255)/256, 256, 0, stream>>>(fp_out, keypoints, ws_small, lm_out);
  k6_tri<<<(NF_*3 + 255)/256, 256, 0, stream>>>(tri, ws_small, tri_out);
}